// Round 1
// 450.057 us; speedup vs baseline: 1.0970x; 1.0970x over previous
//
#include <hip/hip_runtime.h>
#include <cmath>

#define NN 200000
#define NE 600000

typedef __bf16 bf16x8 __attribute__((ext_vector_type(8)));
typedef float f32x4 __attribute__((ext_vector_type(4)));

#define LOG2E 1.44269504088896340736f
__device__ __forceinline__ float fexp2(float x) { return __builtin_amdgcn_exp2f(x); }
__device__ __forceinline__ float frcp(float x) { return __builtin_amdgcn_rcpf(x); }
__device__ __forceinline__ float sigm(float v) { return frcp(1.0f + fexp2(-LOG2E * v)); }
__device__ __forceinline__ float ftanh(float v) {
  float t = fexp2(-2.0f * LOG2E * fabsf(v));
  float r = (1.0f - t) * frcp(1.0f + t);
  return __builtin_copysignf(r, v);
}
__device__ __forceinline__ float eluf(float v) { return v > 0.0f ? v : fexp2(LOG2E * v) - 1.0f; }

__device__ __forceinline__ unsigned short bfr(float f) {  // f32 -> bf16 RNE
  unsigned u = __float_as_uint(f);
  u += 0x7FFFu + ((u >> 16) & 1u);
  return (unsigned short)(u >> 16);
}
__device__ __forceinline__ void bsplit(float v, unsigned short& hi, unsigned short& lo) {
  unsigned short h = bfr(v);
  float hf = __uint_as_float(((unsigned)h) << 16);
  hi = h;
  lo = bfr(v - hf);
}

// ---------------- ws layout (float offsets) ----------------
// x1 [25,600,000] @0 ; deg(int)[200,000] @25,600,000 ; rwt0[128] @25,800,000 ;
// rwh0[384] @25,800,128 ; packed bf16 weight frags (shorts) @float 25,800,512:
//   w0ph 49152 | w0pl 49152 | w1ph 16384 | w1pl 16384 | w2ph 98304 | w2pl 98304

__global__ __launch_bounds__(256) void hist_kernel(const int* __restrict__ dst,
                                                   int* __restrict__ deg) {
  int e = blockIdx.x * 256 + threadIdx.x;
  if (e < NE) atomicAdd(&deg[dst[e]], 1);
}

__global__ __launch_bounds__(512) void prep_kernel(const float* __restrict__ attw0,
                                                   const float* __restrict__ whh0,
                                                   float* __restrict__ rwt0,
                                                   float* __restrict__ rwh0) {
  int t = threadIdx.x;
  if (t < 128) {
    float s = 0.f;
    for (int k = 0; k < 128; k++) s += attw0[t * 128 + k];
    rwt0[t] = s;
  } else {
    int j = t - 128;
    float s = 0.f;
    for (int k = 0; k < 128; k++) s += whh0[j * 128 + k];
    rwh0[j] = s;
  }
}

// Pack weights into MFMA B-fragment order, split hi/lo bf16:
// frag[((nt*4+ks)*64+lane)*8 + j] = W[nt*16+(lane&15)][ks*32+(lane>>4)*8+j]
__global__ __launch_bounds__(256) void pack_kernel(
    const float* __restrict__ wih0, const float* __restrict__ tw1,
    const float* __restrict__ wih1, const float* __restrict__ whh1,
    unsigned short* __restrict__ w0ph, unsigned short* __restrict__ w0pl,
    unsigned short* __restrict__ w1ph, unsigned short* __restrict__ w1pl,
    unsigned short* __restrict__ w2ph, unsigned short* __restrict__ w2pl) {
  int g = blockIdx.x * 256 + threadIdx.x;  // one 8-element lane-frag
  unsigned short *PH, *PL;
  const float* row;
  int l;
  if (g < 6144) { l = g; PH = w0ph; PL = w0pl; }
  else if (g < 8192) { l = g - 6144; PH = w1ph; PL = w1pl; }
  else if (g < 20480) { l = g - 8192; PH = w2ph; PL = w2pl; }
  else return;
  int lane = l & 63, ks = (l >> 6) & 3, nt = l >> 8;
  int n = nt * 16 + (lane & 15);
  int k0 = ks * 32 + (lane >> 4) * 8;
  if (g < 6144) row = wih0 + n * 128;
  else if (g < 8192) row = tw1 + n * 128;
  else row = (n < 384) ? wih1 + n * 128 : whh1 + (n - 384) * 128;
  unsigned uh[4], ul[4];
  for (int p = 0; p < 4; p++) {
    unsigned short ah, al, bh, bl;
    bsplit(row[k0 + 2 * p], ah, al);
    bsplit(row[k0 + 2 * p + 1], bh, bl);
    uh[p] = (unsigned)ah | ((unsigned)bh << 16);
    ul[p] = (unsigned)al | ((unsigned)bl << 16);
  }
  *(uint4*)&PH[l * 8] = make_uint4(uh[0], uh[1], uh[2], uh[3]);
  *(uint4*)&PL[l * 8] = make_uint4(ul[0], ul[1], ul[2], ul[3]);
}

#define MFMA3(accv, ah, al, bh, bl)                                          \
  accv = __builtin_amdgcn_mfma_f32_16x16x32_bf16(ah, bh, accv, 0, 0, 0);     \
  accv = __builtin_amdgcn_mfma_f32_16x16x32_bf16(ah, bl, accv, 0, 0, 0);     \
  accv = __builtin_amdgcn_mfma_f32_16x16x32_bf16(al, bh, accv, 0, 0, 0);

// ---------------- layer 0: M=64 nodes/block, 512 threads (8 waves) ----------------
// Waves split N=384 8-ways (nt = g*8 + wv); each block reads the packed w0 set ONCE,
// amortized over 64 nodes (2x fewer weight bytes/node than M=32).
__global__ __launch_bounds__(512, 4) void layer0_kernel(
    const float* __restrict__ x, const float* __restrict__ tb0,
    const unsigned short* __restrict__ w0ph, const unsigned short* __restrict__ w0pl,
    const float* __restrict__ bih0, const float* __restrict__ bhh0,
    const float* __restrict__ rwt0, const float* __restrict__ rwh0,
    const int* __restrict__ deg, float* __restrict__ x1) {
  __shared__ float s_lds[64];
  __shared__ float deg_lds[64];
  __shared__ unsigned short csh[64 * 136];
  __shared__ unsigned short csl[64 * 136];

  const int tid = threadIdx.x;
  const int lane = tid & 63;
  const int wv = tid >> 6;  // 0..7
  const int n0 = blockIdx.x * 64;

  if (tid < 64) deg_lds[tid] = (float)deg[n0 + tid];

  // s_m = rowsum(x[m])
  {
    int m = tid >> 3, c = (tid & 7) * 16;
    const float4* xr = (const float4*)(x + (size_t)(n0 + m) * 128 + c);
    float a = 0.f;
#pragma unroll
    for (int q = 0; q < 4; q++) { float4 v = xr[q]; a += v.x + v.y + v.z + v.w; }
#pragma unroll
    for (int o = 1; o < 8; o <<= 1) a += __shfl_xor(a, o, 64);
    if ((tid & 7) == 0) s_lds[m] = a;
  }
  __syncthreads();

  // cs0[m][k] = elu(s_m * rwt0[k] + tb0[k]) -> split bf16 LDS
  {
    int m = tid >> 3, c0 = (tid & 7) * 16;
    float s = s_lds[m];
#pragma unroll
    for (int q = 0; q < 4; q++) {
      int k = c0 + q * 4;
      unsigned short h0, l0, h1, l1, h2, l2, h3, l3;
      bsplit(eluf(fmaf(s, rwt0[k], tb0[k])), h0, l0);
      bsplit(eluf(fmaf(s, rwt0[k + 1], tb0[k + 1])), h1, l1);
      bsplit(eluf(fmaf(s, rwt0[k + 2], tb0[k + 2])), h2, l2);
      bsplit(eluf(fmaf(s, rwt0[k + 3], tb0[k + 3])), h3, l3);
      *(uint2*)&csh[m * 136 + k] =
          make_uint2((unsigned)h0 | ((unsigned)h1 << 16), (unsigned)h2 | ((unsigned)h3 << 16));
      *(uint2*)&csl[m * 136 + k] =
          make_uint2((unsigned)l0 | ((unsigned)l1 << 16), (unsigned)l2 | ((unsigned)l3 << 16));
    }
  }
  __syncthreads();

  // gi = cs0 @ wih0^T via split-bf16 MFMA; per wave: 4 m-tiles x 3 gate-tiles
  const int mrow = lane & 15;
  const int kq = (lane >> 4) * 8;
  const int quad = lane >> 4;
  f32x4 acc[4][3] = {};
#pragma unroll
  for (int ks = 0; ks < 4; ks++) {
    bf16x8 ah[4], al[4];
#pragma unroll
    for (int mt = 0; mt < 4; mt++) {
      ah[mt] = *(const bf16x8*)&csh[(mt * 16 + mrow) * 136 + ks * 32 + kq];
      al[mt] = *(const bf16x8*)&csl[(mt * 16 + mrow) * 136 + ks * 32 + kq];
    }
#pragma unroll
    for (int g = 0; g < 3; g++) {
      int nt = g * 8 + wv;
      size_t base = (size_t)((nt * 4 + ks) * 64 + lane) * 8;
      bf16x8 bh = *(const bf16x8*)&w0ph[base];
      bf16x8 bl = *(const bf16x8*)&w0pl[base];
#pragma unroll
      for (int mt = 0; mt < 4; mt++) { MFMA3(acc[mt][g], ah[mt], al[mt], bh, bl); }
    }
  }

  // GRU epilogue (h = s broadcast, gh = s*rwh0 + bhh0), scale by deg
  const int j = wv * 16 + mrow;
  float bir = bih0[j], biz = bih0[j + 128], bin_ = bih0[j + 256];
  float bhr = bhh0[j], bhz = bhh0[j + 128], bhn = bhh0[j + 256];
  float rwr = rwh0[j], rwz = rwh0[j + 128], rwn = rwh0[j + 256];
#pragma unroll
  for (int mt = 0; mt < 4; mt++) {
#pragma unroll
    for (int reg = 0; reg < 4; reg++) {
      int m = mt * 16 + quad * 4 + reg;
      float s = s_lds[m];
      float dd = deg_lds[m];
      float gir = acc[mt][0][reg] + bir;
      float giz = acc[mt][1][reg] + biz;
      float gin = acc[mt][2][reg] + bin_;
      float ghr = fmaf(s, rwr, bhr);
      float ghz = fmaf(s, rwz, bhz);
      float ghn = fmaf(s, rwn, bhn);
      float r = sigm(gir + ghr);
      float z = sigm(giz + ghz);
      float nn2 = ftanh(fmaf(r, ghn, gin));
      x1[(size_t)(n0 + m) * 128 + j] = dd * ((1.f - z) * nn2 + z * s);
    }
  }
}

// ---------------- layer 1: M=64 nodes/block, 512 threads (8 waves) ----------------
// Dynamic LDS (69632 B > 64 KB static limit). Phase A: GEMM1 (cs) + gh GEMM (h@whh1^T,
// independent of cs) before the barrier; Phase B: gi GEMM (cs@wih1^T).
__global__ __launch_bounds__(512, 2) void layer1_kernel(
    const float* __restrict__ x1, const float* __restrict__ tb1,
    const unsigned short* __restrict__ w1ph, const unsigned short* __restrict__ w1pl,
    const unsigned short* __restrict__ w2ph, const unsigned short* __restrict__ w2pl,
    const float* __restrict__ bih1, const float* __restrict__ bhh1,
    const int* __restrict__ deg, float* __restrict__ out) {
  extern __shared__ unsigned short smem[];
  unsigned short* hh = smem;          // 64*136 = 8704 shorts
  unsigned short* hl = smem + 8704;
  unsigned short* ch = smem + 17408;
  unsigned short* cl = smem + 26112;  // total 34816 shorts = 69632 B
  __shared__ float deg_lds[64];

  const int tid = threadIdx.x;
  const int lane = tid & 63;
  const int wv = tid >> 6;  // 0..7
  const int n0 = blockIdx.x * 64;
  const int mrow = lane & 15;
  const int kq = (lane >> 4) * 8;
  const int quad = lane >> 4;

  if (tid < 64) deg_lds[tid] = (float)deg[n0 + tid];

  // stage h = x1 tile, split bf16
  {
    int m = tid >> 3, c0 = (tid & 7) * 16;
    const float4* xr = (const float4*)(x1 + (size_t)(n0 + m) * 128 + c0);
#pragma unroll
    for (int q = 0; q < 4; q++) {
      float4 v = xr[q];
      unsigned short h0, l0, h1, l1, h2, l2, h3, l3;
      bsplit(v.x, h0, l0); bsplit(v.y, h1, l1);
      bsplit(v.z, h2, l2); bsplit(v.w, h3, l3);
      *(uint2*)&hh[m * 136 + c0 + q * 4] =
          make_uint2((unsigned)h0 | ((unsigned)h1 << 16), (unsigned)h2 | ((unsigned)h3 << 16));
      *(uint2*)&hl[m * 136 + c0 + q * 4] =
          make_uint2((unsigned)l0 | ((unsigned)l1 << 16), (unsigned)l2 | ((unsigned)l3 << 16));
    }
  }
  __syncthreads();

  // Phase A: acc1 = (h @ tw1^T) slice  +  acc2[.][3..5] = (h @ whh1^T) slice
  f32x4 acc1[4] = {};
  f32x4 acc2[4][6] = {};
#pragma unroll
  for (int ks = 0; ks < 4; ks++) {
    bf16x8 xh[4], xl[4];
#pragma unroll
    for (int mt = 0; mt < 4; mt++) {
      xh[mt] = *(const bf16x8*)&hh[(mt * 16 + mrow) * 136 + ks * 32 + kq];
      xl[mt] = *(const bf16x8*)&hl[(mt * 16 + mrow) * 136 + ks * 32 + kq];
    }
    {
      size_t base = (size_t)((wv * 4 + ks) * 64 + lane) * 8;
      bf16x8 bh = *(const bf16x8*)&w1ph[base];
      bf16x8 bl = *(const bf16x8*)&w1pl[base];
#pragma unroll
      for (int mt = 0; mt < 4; mt++) { MFMA3(acc1[mt], xh[mt], xl[mt], bh, bl); }
    }
#pragma unroll
    for (int g = 0; g < 3; g++) {
      int nt = 24 + g * 8 + wv;
      size_t base = (size_t)((nt * 4 + ks) * 64 + lane) * 8;
      bf16x8 bh = *(const bf16x8*)&w2ph[base];
      bf16x8 bl = *(const bf16x8*)&w2pl[base];
#pragma unroll
      for (int mt = 0; mt < 4; mt++) { MFMA3(acc2[mt][3 + g], xh[mt], xl[mt], bh, bl); }
    }
  }

  // cs = elu(t1 + tb1) -> split bf16 LDS (pair-lane packed b32 stores)
  {
    float tbj = tb1[wv * 16 + mrow];
#pragma unroll
    for (int mt = 0; mt < 4; mt++) {
#pragma unroll
      for (int reg = 0; reg < 4; reg++) {
        int m = mt * 16 + quad * 4 + reg;
        unsigned short vh, vl;
        bsplit(eluf(acc1[mt][reg] + tbj), vh, vl);
        unsigned pv = (unsigned)vh | ((unsigned)vl << 16);
        unsigned pu = __shfl_xor(pv, 1, 64);
        if ((lane & 1) == 0) {
          int jc = wv * 16 + mrow;  // mrow even here
          unsigned hpack = (pv & 0xFFFFu) | (pu << 16);
          unsigned lpack = (pv >> 16) | (pu & 0xFFFF0000u);
          *(unsigned*)&ch[m * 136 + jc] = hpack;
          *(unsigned*)&cl[m * 136 + jc] = lpack;
        }
      }
    }
  }
  __syncthreads();

  // Phase B: acc2[.][0..2] = (cs @ wih1^T) slice
#pragma unroll
  for (int ks = 0; ks < 4; ks++) {
    bf16x8 ah[4], al[4];
#pragma unroll
    for (int mt = 0; mt < 4; mt++) {
      ah[mt] = *(const bf16x8*)&ch[(mt * 16 + mrow) * 136 + ks * 32 + kq];
      al[mt] = *(const bf16x8*)&cl[(mt * 16 + mrow) * 136 + ks * 32 + kq];
    }
#pragma unroll
    for (int g = 0; g < 3; g++) {
      int nt = g * 8 + wv;
      size_t base = (size_t)((nt * 4 + ks) * 64 + lane) * 8;
      bf16x8 bh = *(const bf16x8*)&w2ph[base];
      bf16x8 bl = *(const bf16x8*)&w2pl[base];
#pragma unroll
      for (int mt = 0; mt < 4; mt++) { MFMA3(acc2[mt][g], ah[mt], al[mt], bh, bl); }
    }
  }

  // GRU epilogue + deg scale
  const int j = wv * 16 + mrow;
  float bir = bih1[j], biz = bih1[j + 128], bin_ = bih1[j + 256];
  float bhr = bhh1[j], bhz = bhh1[j + 128], bhn = bhh1[j + 256];
#pragma unroll
  for (int mt = 0; mt < 4; mt++) {
#pragma unroll
    for (int reg = 0; reg < 4; reg++) {
      int m = mt * 16 + quad * 4 + reg;
      float dd = deg_lds[m];
      float gir = acc2[mt][0][reg] + bir;
      float giz = acc2[mt][1][reg] + biz;
      float gin = acc2[mt][2][reg] + bin_;
      float ghr = acc2[mt][3][reg] + bhr;
      float ghz = acc2[mt][4][reg] + bhz;
      float ghn = acc2[mt][5][reg] + bhn;
      float r = sigm(gir + ghr);
      float z = sigm(giz + ghz);
      float nn2 = ftanh(fmaf(r, ghn, gin));
      float hfull = (float)(*(const __bf16*)&hh[m * 136 + j]) +
                    (float)(*(const __bf16*)&hl[m * 136 + j]);
      out[(size_t)(n0 + m) * 128 + j] = dd * ((1.f - z) * nn2 + z * hfull);
    }
  }
}

extern "C" void kernel_launch(void* const* d_in, const int* in_sizes, int n_in,
                              void* d_out, int out_size, void* d_ws, size_t ws_size,
                              hipStream_t stream) {
  const float* x     = (const float*)d_in[0];
  const int*   edge  = (const int*)d_in[1];
  const float* attw0 = (const float*)d_in[4];
  const float* attb0 = (const float*)d_in[5];
  const float* wih0  = (const float*)d_in[6];
  const float* whh0  = (const float*)d_in[7];
  const float* bih0  = (const float*)d_in[8];
  const float* bhh0  = (const float*)d_in[9];
  const float* attw1 = (const float*)d_in[12];
  const float* attb1 = (const float*)d_in[13];
  const float* wih1  = (const float*)d_in[14];
  const float* whh1  = (const float*)d_in[15];
  const float* bih1  = (const float*)d_in[16];
  const float* bhh1  = (const float*)d_in[17];

  float* ws   = (float*)d_ws;
  float* x1   = ws;
  int*   deg  = (int*)(ws + 25600000);
  float* rwt0 = ws + 25800000;
  float* rwh0 = ws + 25800128;
  unsigned short* wp = (unsigned short*)(ws + 25800512);
  unsigned short* w0ph = wp;             // 49152 shorts
  unsigned short* w0pl = wp + 49152;
  unsigned short* w1ph = wp + 98304;     // 16384
  unsigned short* w1pl = wp + 114688;
  unsigned short* w2ph = wp + 131072;    // 98304
  unsigned short* w2pl = wp + 229376;    // end 327680 shorts

  const int* dst = edge + NE;  // edge_index[1]

  static bool attr_done = false;
  if (!attr_done) {
    hipFuncSetAttribute(reinterpret_cast<const void*>(layer1_kernel),
                        hipFuncAttributeMaxDynamicSharedMemorySize, 69632);
    attr_done = true;
  }

  hipMemsetAsync(deg, 0, NN * sizeof(int), stream);
  hist_kernel<<<(NE + 255) / 256, 256, 0, stream>>>(dst, deg);
  prep_kernel<<<1, 512, 0, stream>>>(attw0, whh0, rwt0, rwh0);
  pack_kernel<<<80, 256, 0, stream>>>(wih0, attw1, wih1, whh1,
                                      w0ph, w0pl, w1ph, w1pl, w2ph, w2pl);
  layer0_kernel<<<NN / 64, 512, 0, stream>>>(x, attb0, w0ph, w0pl, bih0, bhh0,
                                             rwt0, rwh0, deg, x1);
  layer1_kernel<<<NN / 64, 512, 69632, stream>>>(x1, attb1, w1ph, w1pl, w2ph, w2pl,
                                                 bih1, bhh1, deg, (float*)d_out);
}